// Round 5
// baseline (150.869 us; speedup 1.0000x reference)
//
#include <hip/hip_runtime.h>

typedef unsigned short u16;
typedef unsigned int   u32;
typedef __attribute__((ext_vector_type(4)))  float  f32x4;
typedef __attribute__((ext_vector_type(16))) float  f32x16;
typedef __attribute__((ext_vector_type(8)))  __bf16 bf16x8;
typedef __attribute__((ext_vector_type(8)))  u16    u16x8;
typedef __attribute__((ext_vector_type(2)))  u32    u32x2;
typedef __attribute__((ext_vector_type(4)))  u32    u32x4;

#define GLB_AS __attribute__((address_space(1)))
#define LDS_AS __attribute__((address_space(3)))

__device__ __forceinline__ void gload16(const void* g, void* l) {
  __builtin_amdgcn_global_load_lds((const GLB_AS u32*)g, (LDS_AS u32*)l, 16, 0, 0);
}

// Pinned barrier: drain all mem ops, then workgroup barrier (race-proof, R4-verified).
__device__ __forceinline__ void pinned_barrier() {
  __builtin_amdgcn_sched_barrier(0);
  asm volatile("s_waitcnt vmcnt(0) lgkmcnt(0)" ::: "memory");
  __builtin_amdgcn_sched_barrier(0);
  __builtin_amdgcn_s_barrier();
  __builtin_amdgcn_sched_barrier(0);
}

__device__ __forceinline__ u16 f2bf(float f) {
  u32 x = __builtin_bit_cast(u32, f);
  return (u16)((x + 0x7fffu + ((x >> 16) & 1u)) >> 16);
}
__device__ __forceinline__ float bf2f(u16 h) {
  u32 x = ((u32)h) << 16;
  return __builtin_bit_cast(float, x);
}
// packed f32x2 -> bf16x2 (RNE), lo = a, hi = b
__device__ __forceinline__ u32 cvtpk_bf16(float a, float b) {
  u32 r;
  asm("v_cvt_pk_bf16_f32 %0, %1, %2" : "=v"(r) : "v"(a), "v"(b));
  return r;
}

// ---------------- fused cast fp32 -> bf16 (all 7 arrays, one launch) ----------------
__global__ void cast_all(const float* __restrict__ q, const float* __restrict__ k,
                         const float* __restrict__ v, const float* __restrict__ Wq,
                         const float* __restrict__ Wk, const float* __restrict__ Wv,
                         const float* __restrict__ Wo,
                         u16* __restrict__ qb, u16* __restrict__ kb, u16* __restrict__ vb,
                         u16* __restrict__ Wqb, u16* __restrict__ Wkb, u16* __restrict__ Wvb,
                         u16* __restrict__ Wob) {
  int i = blockIdx.x * 256 + threadIdx.x;     // float4 index; total 4,194,304
  const float* src;
  u16* dst;
  int off;
  if (i < 3145728) {
    int seg = i >> 20;
    off = i & 1048575;
    src = seg == 0 ? q : seg == 1 ? k : v;
    dst = seg == 0 ? qb : seg == 1 ? kb : vb;
  } else {
    int wi = i - 3145728;
    int seg = wi >> 18;
    off = wi & 262143;
    src = seg == 0 ? Wq : seg == 1 ? Wk : seg == 2 ? Wv : Wo;
    dst = seg == 0 ? Wqb : seg == 1 ? Wkb : seg == 2 ? Wvb : Wob;
  }
  float4 f = reinterpret_cast<const float4*>(src)[off];
  ushort4 o;
  o.x = f2bf(f.x); o.y = f2bf(f.y); o.z = f2bf(f.z); o.w = f2bf(f.w);
  reinterpret_cast<ushort4*>(dst)[off] = o;
}

// ---------------- GEMM core: double-buffered, prefetch-before-compute, pinned ------
__device__ __forceinline__ void gemm_core(const u16* __restrict__ Ag, const u16* __restrict__ Bg,
                                          int K, int m0, int n0,
                                          u16 (*Al)[128 * 32], u16 (*Bl)[128 * 32],
                                          f32x4 acc[4][4]) {
  const int t = threadIdx.x;
  const int l = t & 63;
  const int c = l & 15, g = l >> 4;
  const int w = t >> 6, wr = w >> 1, wc = w & 1;

  auto stage = [&](int k0, int buf) {
#pragma unroll
    for (int i = 0; i < 2; i++) {
      int idx = i * 256 + t;
      int row = idx >> 2;
      int kc  = (idx & 3) * 8;
      gload16(Ag + (size_t)(m0 + row) * K + (k0 + kc), Al[buf] + (i * 256 + (t & 192)) * 8);
      gload16(Bg + (size_t)(n0 + row) * K + (k0 + kc), Bl[buf] + (i * 256 + (t & 192)) * 8);
    }
  };

#pragma unroll
  for (int mi = 0; mi < 4; mi++)
#pragma unroll
    for (int ni = 0; ni < 4; ni++) acc[mi][ni] = f32x4{0.f, 0.f, 0.f, 0.f};

  stage(0, 0);
  pinned_barrier();

  const int nk = K >> 5;
  for (int ik = 0; ik < nk; ik++) {
    const int cur = ik & 1;
    if (ik + 1 < nk) stage((ik + 1) << 5, cur ^ 1);
    __builtin_amdgcn_sched_barrier(0);

    bf16x8 af[4], bfr[4];
#pragma unroll
    for (int mi = 0; mi < 4; mi++)
      af[mi] = *(const bf16x8*)(Al[cur] + (wr * 64 + mi * 16 + c) * 32 + g * 8);
#pragma unroll
    for (int ni = 0; ni < 4; ni++)
      bfr[ni] = *(const bf16x8*)(Bl[cur] + (wc * 64 + ni * 16 + c) * 32 + g * 8);
#pragma unroll
    for (int mi = 0; mi < 4; mi++)
#pragma unroll
      for (int ni = 0; ni < 4; ni++)
        acc[mi][ni] = __builtin_amdgcn_mfma_f32_16x16x32_bf16(af[mi], bfr[ni], acc[mi][ni], 0, 0, 0);

    pinned_barrier();
  }
}

// ---------------- fused QKV projection ----------------
__global__ __launch_bounds__(256, 2) void qkv_gemm(
    const u16* __restrict__ qb, const u16* __restrict__ kb, const u16* __restrict__ vb,
    const u16* __restrict__ Wqb, const u16* __restrict__ Wkb, const u16* __restrict__ Wvb,
    const float* __restrict__ bq, const float* __restrict__ bk, const float* __restrict__ bv,
    u16* __restrict__ Qp, u16* __restrict__ Kp, u16* __restrict__ Vt) {
  __shared__ alignas(16) u16 Al[2][128 * 32];
  __shared__ alignas(16) u16 Bl[2][128 * 32];
  const int z = blockIdx.z;
  const int bid = blockIdx.x;
  const u16 *Ag, *Bg;
  const float* bias;
  if (z == 0) { Ag = qb; Bg = Wqb; bias = bq; }
  else if (z == 1) { Ag = kb; Bg = Wkb; bias = bk; }
  else { Ag = Wvb; Bg = vb; bias = bv; }
  int mt, nt;
  if (z < 2) { mt = bid >> 3; nt = bid & 7; }
  else       { mt = bid & 7;  nt = bid >> 3; }
  const int m0 = mt * 128, n0 = nt * 128;

  f32x4 acc[4][4];
  gemm_core(Ag, Bg, 1024, m0, n0, Al, Bl, acc);

  const int t = threadIdx.x, l = t & 63, w = t >> 6;
  const int c = l & 15, g = l >> 4, wr = w >> 1, wc = w & 1;
#pragma unroll
  for (int mi = 0; mi < 4; mi++) {
#pragma unroll
    for (int ni = 0; ni < 4; ni++) {
      const int gcol = n0 + wc * 64 + ni * 16 + c;
#pragma unroll
      for (int r = 0; r < 4; r++) {
        const int grow = m0 + wr * 64 + mi * 16 + g * 4 + r;
        float val = acc[mi][ni][r];
        if (z < 2) {
          val += bias[gcol];
          u16* out = (z == 0) ? Qp : Kp;
          out[(size_t)grow * 1024 + gcol] = f2bf(val);
        } else {
          val += bias[grow];
          const int hh = grow >> 6, dk = grow & 63, bb = gcol >> 11, ss = gcol & 2047;
          Vt[(((size_t)(bb * 16 + hh) * 64 + dk) << 11) + ss] = f2bf(val);
        }
      }
    }
  }
}

// ---------------- final output projection (fp32 out) ----------------
__global__ __launch_bounds__(256, 2) void out_gemm(
    const u16* __restrict__ AO, const u16* __restrict__ Wob,
    const float* __restrict__ bo, float* __restrict__ out) {
  __shared__ alignas(16) u16 Al[2][128 * 32];
  __shared__ alignas(16) u16 Bl[2][128 * 32];
  const int bid = blockIdx.x;
  const int m0 = (bid >> 3) * 128, n0 = (bid & 7) * 128;
  f32x4 acc[4][4];
  gemm_core(AO, Wob, 1024, m0, n0, Al, Bl, acc);
  const int t = threadIdx.x, l = t & 63, w = t >> 6;
  const int c = l & 15, g = l >> 4, wr = w >> 1, wc = w & 1;
#pragma unroll
  for (int mi = 0; mi < 4; mi++)
#pragma unroll
    for (int ni = 0; ni < 4; ni++) {
      const int gcol = n0 + wc * 64 + ni * 16 + c;
      const float bb = bo[gcol];
#pragma unroll
      for (int r = 0; r < 4; r++) {
        const int grow = m0 + wr * 64 + mi * 16 + g * 4 + r;
        out[(size_t)grow * 1024 + gcol] = acc[mi][ni][r] + bb;
      }
    }
}

// ---------------- flash attention v4: 32x32 MFMA, in-register P (T12) --------------
// Grid (32 q-blocks, 32 (b,h)); 128 threads = 2 waves, each wave owns 32 q-rows.
// Swapped QK^T via mfma_32x32x16(K, Q) -> S^T: lane owns q-column (q = lane&31),
// 32 scores spread over regs/hi. Softmax lane-local + one shfl_xor(32).
// P -> PV B-operand entirely in-register: cvt_pk pairs + permlane32_swap.
__global__ __launch_bounds__(128, 2) void attn_fwd(
    const u16* __restrict__ Qb, const u16* __restrict__ Kb,
    const u16* __restrict__ Vt, u16* __restrict__ AO) {
  __shared__ alignas(16) u16 Kl[2][64 * 64];   // [n 0..63][dk octets, xor-swizzled]
  __shared__ alignas(16) u16 Vl[2][64 * 64];   // [dk 0..63][s octets, xor-swizzled]
  const int bh = blockIdx.y, b = bh >> 4, h = bh & 15;
  const int q0 = blockIdx.x * 64;
  const int t = threadIdx.x, w = t >> 6, l = t & 63;
  const int q = l & 31, hi = l >> 5;

  auto stage = [&](int kv, int buf) {
#pragma unroll
    for (int i = 0; i < 4; i++) {
      int idx  = i * 128 + t;              // 512 chunks of 16B per tile
      int row  = idx >> 3;
      int col8 = ((idx & 7) ^ (row & 7)) * 8;
      gload16(Kb + ((size_t)(b * 2048 + kv + row) * 1024 + h * 64 + col8),
              Kl[buf] + (i * 128 + (t & 64)) * 8);
      gload16(Vt + ((size_t)(bh * 64 + row) * 2048 + kv + col8),
              Vl[buf] + (i * 128 + (t & 64)) * 8);
    }
  };

  stage(0, 0);
  __builtin_amdgcn_sched_barrier(0);

  // Q fragments: B-operand of 32x32x16, col q, k-octet = hi. Pre-scaled log2(e)/8.
  const float QSCALE = 0.125f * 1.44269504f;
  bf16x8 qf[4];
  {
    const u16* qp = Qb + ((size_t)(b * 2048 + q0 + w * 32 + q) * 1024 + h * 64);
#pragma unroll
    for (int ks = 0; ks < 4; ks++) {
      u16x8 raw = *(const u16x8*)(qp + ks * 16 + hi * 8);
      u16x8 sc;
#pragma unroll
      for (int j = 0; j < 8; j++) sc[j] = f2bf(bf2f(raw[j]) * QSCALE);
      qf[ks] = __builtin_bit_cast(bf16x8, sc);
    }
  }

  f32x16 oT[2];
#pragma unroll
  for (int dt = 0; dt < 2; dt++)
#pragma unroll
    for (int r = 0; r < 16; r++) oT[dt][r] = 0.f;
  float mrun = -3.0e38f, lsum = 0.f;
  const float THR = 11.54f;   // 8 nats in log2 units

  pinned_barrier();   // tile 0 staged

  for (int it = 0; it < 32; it++) {
    const int cur = it & 1;
    if (it + 1 < 32) stage((it + 1) * 64, cur ^ 1);
    __builtin_amdgcn_sched_barrier(0);

    // QK^T: st[ni] = S^T tile, row n = ni*32 + (r&3)+8*(r>>2)+4*hi, col q
    f32x16 st[2];
#pragma unroll
    for (int ni = 0; ni < 2; ni++) {
#pragma unroll
      for (int r = 0; r < 16; r++) st[ni][r] = 0.f;
#pragma unroll
      for (int ks = 0; ks < 4; ks++) {
        const int krow = ni * 32 + q;
        bf16x8 kf = *(const bf16x8*)((const char*)Kl[cur] + krow * 128 +
                                     (((ks * 2 + hi) * 16) ^ ((krow & 7) << 4)));
        st[ni] = __builtin_amdgcn_mfma_f32_32x32x16_bf16(kf, qf[ks], st[ni], 0, 0, 0);
      }
    }

    // column max: in-lane tree + one cross-half shuffle
    float tmax = st[0][0];
#pragma unroll
    for (int ni = 0; ni < 2; ni++)
#pragma unroll
      for (int r = 0; r < 16; r++) tmax = fmaxf(tmax, st[ni][r]);
    tmax = fmaxf(tmax, __shfl_xor(tmax, 32));

    // defer-max (rare after tile 0); f is lane-local (q-column local)
    if (__any(tmax > mrun + THR)) {
      const float mnew = fmaxf(mrun, tmax);
      const float f    = __builtin_amdgcn_exp2f(mrun - mnew);
#pragma unroll
      for (int dt = 0; dt < 2; dt++)
#pragma unroll
        for (int r = 0; r < 16; r++) oT[dt][r] *= f;
      lsum *= f;
      mrun = mnew;
    }

    // P = exp2(st - mrun); pack + permlane32_swap into PV B-operand frags.
    // frag[2*ni+p] covers n = (2*ni+p)*16 + 8*hi + j  (j = 0..7).
    bf16x8 pf[4];
    float ts = 0.f;
#pragma unroll
    for (int ni = 0; ni < 2; ni++) {
      float p[16];
#pragma unroll
      for (int r = 0; r < 16; r++) {
        p[r] = __builtin_amdgcn_exp2f(st[ni][r] - mrun);
        ts += p[r];
      }
#pragma unroll
      for (int pp = 0; pp < 2; pp++) {
        u32 Wa = cvtpk_bf16(p[8 * pp + 0], p[8 * pp + 1]);
        u32 Wb = cvtpk_bf16(p[8 * pp + 2], p[8 * pp + 3]);
        u32 Wc = cvtpk_bf16(p[8 * pp + 4], p[8 * pp + 5]);
        u32 Wd = cvtpk_bf16(p[8 * pp + 6], p[8 * pp + 7]);
        u32x2 r0 = __builtin_amdgcn_permlane32_swap(Wa, Wc, false, false);  // {w0, w2}
        u32x2 r1 = __builtin_amdgcn_permlane32_swap(Wb, Wd, false, false);  // {w1, w3}
        u32x4 fw;
        fw.x = r0.x; fw.y = r1.x; fw.z = r0.y; fw.w = r1.y;
        pf[ni * 2 + pp] = __builtin_bit_cast(bf16x8, fw);
      }
    }
    lsum += ts;

    // PV: oT[dt] += V^T x P^T ; A = V^T rows (d), B = P frags
#pragma unroll
    for (int dt = 0; dt < 2; dt++) {
#pragma unroll
      for (int ks = 0; ks < 4; ks++) {
        const int vrow = dt * 32 + q;
        bf16x8 vf = *(const bf16x8*)((const char*)Vl[cur] + vrow * 128 +
                                     (((ks * 2 + hi) * 16) ^ ((vrow & 7) << 4)));
        oT[dt] = __builtin_amdgcn_mfma_f32_32x32x16_bf16(vf, pf[ks], oT[dt], 0, 0, 0);
      }
    }

    pinned_barrier();
  }

  // epilogue: reduce lsum across halves, scale, store packed pairs
  lsum += __shfl_xor(lsum, 32);
  const float li = 1.f / lsum;
  u16* aop = AO + (size_t)(b * 2048 + q0 + w * 32 + q) * 1024 + h * 64;
#pragma unroll
  for (int dt = 0; dt < 2; dt++)
#pragma unroll
    for (int rq = 0; rq < 4; rq++) {
      const int dbase = dt * 32 + rq * 8 + hi * 4;
      u32x2 pr;
      pr.x = cvtpk_bf16(oT[dt][4 * rq + 0] * li, oT[dt][4 * rq + 1] * li);
      pr.y = cvtpk_bf16(oT[dt][4 * rq + 2] * li, oT[dt][4 * rq + 3] * li);
      *(u32x2*)(aop + dbase) = pr;
    }
}

// ---------------- launch ----------------
extern "C" void kernel_launch(void* const* d_in, const int* in_sizes, int n_in,
                              void* d_out, int out_size, void* d_ws, size_t ws_size,
                              hipStream_t stream) {
  const float* q  = (const float*)d_in[0];
  const float* k  = (const float*)d_in[1];
  const float* v  = (const float*)d_in[2];
  const float* Wq = (const float*)d_in[3];
  const float* bq = (const float*)d_in[4];
  const float* Wk = (const float*)d_in[5];
  const float* bk = (const float*)d_in[6];
  const float* Wv = (const float*)d_in[7];
  const float* bv = (const float*)d_in[8];
  const float* Wo = (const float*)d_in[9];
  const float* bo = (const float*)d_in[10];

  char* ws = (char*)d_ws;
  const size_t MB = 1u << 20;
  u16* qb  = (u16*)(ws + 0 * MB);
  u16* kb  = (u16*)(ws + 8 * MB);
  u16* vb  = (u16*)(ws + 16 * MB);
  u16* Wqb = (u16*)(ws + 24 * MB);
  u16* Wkb = (u16*)(ws + 26 * MB);
  u16* Wvb = (u16*)(ws + 28 * MB);
  u16* Wob = (u16*)(ws + 30 * MB);
  u16* Qp  = (u16*)(ws + 32 * MB);
  u16* Kp  = (u16*)(ws + 40 * MB);
  u16* Vtp = (u16*)(ws + 48 * MB);
  u16* AO  = (u16*)(ws + 56 * MB);

  cast_all<<<16384, 256, 0, stream>>>(q, k, v, Wq, Wk, Wv, Wo,
                                      qb, kb, vb, Wqb, Wkb, Wvb, Wob);
  qkv_gemm<<<dim3(256, 1, 3), 256, 0, stream>>>(qb, kb, vb, Wqb, Wkb, Wvb,
                                                bq, bk, bv, Qp, Kp, Vtp);
  attn_fwd<<<dim3(32, 32), 128, 0, stream>>>(Qp, Kp, Vtp, AO);
  out_gemm<<<256, 256, 0, stream>>>(AO, Wob, bo, (float*)d_out);
}